// Round 19
// baseline (227.831 us; speedup 1.0000x reference)
//
#include <hip/hip_runtime.h>
#include <hip/hip_bf16.h>

#define DMODEL 1024
#define NH     16
#define DKH    64
#define BSZ    2
#define SEQ    2048
#define MROWS  (BSZ*SEQ)      // 4096
#define WELEM  (DMODEL*DMODEL)

typedef __attribute__((ext_vector_type(8))) short short8;
typedef __attribute__((ext_vector_type(4))) float f32x4;

__device__ __forceinline__ ushort f2bf(float f) {
    return __bfloat16_as_ushort(__float2bfloat16(f));
}
__device__ __forceinline__ unsigned pk2(float lo, float hi) {
    return (unsigned)f2bf(lo) | ((unsigned)f2bf(hi) << 16);
}
// Async global->LDS, 16 B/lane. LDS dest = wave-uniform base + lane*16.
__device__ __forceinline__ void load_lds16(const ushort* g, ushort* l) {
    __builtin_amdgcn_global_load_lds(
        (const __attribute__((address_space(1))) unsigned int*)g,
        (__attribute__((address_space(3))) unsigned int*)l, 16, 0, 0);
}

// Merged fp32->bf16 conversion (R17-validated).
__global__ __launch_bounds__(256)
void cvt_all(const float* __restrict__ x,
             const float* __restrict__ W0, const float* __restrict__ W1,
             const float* __restrict__ W2, const float* __restrict__ W3,
             ushort* __restrict__ xbf, ushort* __restrict__ Wcat,
             ushort* __restrict__ Wo)
{
    const int blk = blockIdx.x;
    const float* src;
    ushort* dst;
    int base;
    if (blk < 2048)      { src = x;  dst = xbf;             base = blk * 2048; }
    else if (blk < 2560) { src = W0; dst = Wcat;            base = (blk - 2048) * 2048; }
    else if (blk < 3072) { src = W1; dst = Wcat + WELEM;    base = (blk - 2560) * 2048; }
    else if (blk < 3584) { src = W2; dst = Wcat + 2*WELEM;  base = (blk - 3072) * 2048; }
    else                 { src = W3; dst = Wo;              base = (blk - 3584) * 2048; }
    const size_t off = (size_t)base + threadIdx.x * 8;
    const float4 f0 = *(const float4*)(src + off);
    const float4 f1 = *(const float4*)(src + off + 4);
    uint4 o;
    o.x = pk2(f0.x, f0.y); o.y = pk2(f0.z, f0.w);
    o.z = pk2(f1.x, f1.y); o.w = pk2(f1.z, f1.w);
    *(uint4*)(dst + off) = o;
}

// FUSED QKV GEMM: async staging, BK=64 as two unpadded [128][32] sub-tiles
// (m97 conflict profile preserved; padding is illegal with global_load_lds).
// Barriers per unit work halved vs BK=32. Region 0 (Q) PRE-SCALED by 1/8.
__global__ __launch_bounds__(256)
void gemm_qkv(const ushort* __restrict__ xbf, const ushort* __restrict__ Wcat,
              const float* __restrict__ bq, const float* __restrict__ bk,
              const float* __restrict__ bv,
              ushort* __restrict__ Qh, ushort* __restrict__ Kh,
              ushort* __restrict__ VT)
{
    __shared__ ushort Ash[2][128][32];
    __shared__ ushort Bsh[2][128][32];

    const int t    = threadIdx.x;
    const int m0   = blockIdx.y * 128, n0 = blockIdx.x * 128;
    const int wave = t >> 6;
    const int lane = t & 63;
    const int wr   = (wave >> 1) * 64;
    const int wc   = (wave & 1) * 64;
    const int quad = lane >> 4;
    const int r16  = lane & 15;

    const int row0 = wave * 16 + (lane >> 2);        // staging rows (R18 geom)
    const int row1 = 64 + wave * 16 + (lane >> 2);
    const int ch   = (lane & 3) * 8;

    f32x4 acc[4][4];
    #pragma unroll
    for (int i = 0; i < 4; ++i)
        #pragma unroll
        for (int j = 0; j < 4; ++j)
            acc[i][j] = (f32x4){0.f, 0.f, 0.f, 0.f};

    for (int k0 = 0; k0 < DMODEL; k0 += 64) {
        #pragma unroll
        for (int s = 0; s < 2; ++s) {
            const int kc = k0 + s * 32;
            load_lds16(xbf  + (size_t)(m0 + row0) * DMODEL + kc + ch, &Ash[s][wave * 16][0]);
            load_lds16(xbf  + (size_t)(m0 + row1) * DMODEL + kc + ch, &Ash[s][64 + wave * 16][0]);
            load_lds16(Wcat + (size_t)(n0 + row0) * DMODEL + kc + ch, &Bsh[s][wave * 16][0]);
            load_lds16(Wcat + (size_t)(n0 + row1) * DMODEL + kc + ch, &Bsh[s][64 + wave * 16][0]);
        }
        __syncthreads();

        #pragma unroll
        for (int s = 0; s < 2; ++s) {
            short8 af[4], bf[4];
            #pragma unroll
            for (int i = 0; i < 4; ++i) af[i] = *(const short8*)&Ash[s][wr + i * 16 + r16][quad * 8];
            #pragma unroll
            for (int j = 0; j < 4; ++j) bf[j] = *(const short8*)&Bsh[s][wc + j * 16 + r16][quad * 8];
            #pragma unroll
            for (int i = 0; i < 4; ++i)
                #pragma unroll
                for (int j = 0; j < 4; ++j)
                    acc[i][j] = __builtin_amdgcn_mfma_f32_16x16x32_bf16(af[i], bf[j], acc[i][j], 0, 0, 0);
        }
        __syncthreads();
    }

    const int region = n0 >> 10;
    const float* bp  = (region == 0) ? bq : (region == 1) ? bk : bv;
    ushort* outQK    = (region == 0) ? Qh : Kh;
    const float osc  = (region == 0) ? 0.125f : 1.0f;
    const int nbase  = n0 & 1023;

    #pragma unroll
    for (int i = 0; i < 4; ++i) {
        #pragma unroll
        for (int j = 0; j < 4; ++j) {
            #pragma unroll
            for (int reg = 0; reg < 4; ++reg) {
                const int m  = m0 + wr + i * 16 + quad * 4 + reg;
                const int n  = nbase + wc + j * 16 + r16;
                const float v = (acc[i][j][reg] + bp[n]) * osc;
                const int b = m >> 11, s = m & (SEQ - 1);
                const int h = n >> 6,  dk = n & 63;
                if (region < 2) {
                    outQK[((size_t)(b * NH + h) * SEQ + s) * DKH + dk] = f2bf(v);
                } else {
                    VT[(((size_t)(b * NH + h)) * DKH + dk) * SEQ + s] = f2bf(v);
                }
            }
        }
    }
}

// Output projection: async staging, BK=64 via two sub-tiles. O bf16 head-major.
__global__ __launch_bounds__(256)
void gemm_out(const ushort* __restrict__ O, const ushort* __restrict__ Wo,
              const float* __restrict__ bo, float* __restrict__ out)
{
    __shared__ ushort Ash[2][128][32];
    __shared__ ushort Bsh[2][64][32];

    const int t    = threadIdx.x;
    const int m0   = blockIdx.y * 128, n0 = blockIdx.x * 64;
    const int wave = t >> 6;
    const int lane = t & 63;
    const int wr   = (wave >> 1) * 64;
    const int wc   = (wave & 1) * 32;
    const int quad = lane >> 4;
    const int r16  = lane & 15;

    const int row0 = wave * 16 + (lane >> 2);
    const int row1 = 64 + wave * 16 + (lane >> 2);
    const int ch   = (lane & 3) * 8;

    f32x4 acc[4][2];
    #pragma unroll
    for (int i = 0; i < 4; ++i)
        #pragma unroll
        for (int j = 0; j < 2; ++j)
            acc[i][j] = (f32x4){0.f, 0.f, 0.f, 0.f};

    for (int k0 = 0; k0 < DMODEL; k0 += 64) {
        #pragma unroll
        for (int s = 0; s < 2; ++s) {
            const int kc = k0 + s * 32;                 // head idx kc>>6, col kc&63
            const int ma0 = m0 + row0, ma1 = m0 + row1;
            load_lds16(O + ((size_t)(ma0 >> 11) * NH + (kc >> 6)) * (SEQ * DKH)
                         + (size_t)(ma0 & (SEQ - 1)) * DKH + (kc & 63) + ch,
                       &Ash[s][wave * 16][0]);
            load_lds16(O + ((size_t)(ma1 >> 11) * NH + (kc >> 6)) * (SEQ * DKH)
                         + (size_t)(ma1 & (SEQ - 1)) * DKH + (kc & 63) + ch,
                       &Ash[s][64 + wave * 16][0]);
            load_lds16(Wo + (size_t)(n0 + row0) * DMODEL + kc + ch, &Bsh[s][wave * 16][0]);
        }
        __syncthreads();

        #pragma unroll
        for (int s = 0; s < 2; ++s) {
            short8 af[4], bf[2];
            #pragma unroll
            for (int i = 0; i < 4; ++i) af[i] = *(const short8*)&Ash[s][wr + i * 16 + r16][quad * 8];
            #pragma unroll
            for (int j = 0; j < 2; ++j) bf[j] = *(const short8*)&Bsh[s][wc + j * 16 + r16][quad * 8];
            #pragma unroll
            for (int i = 0; i < 4; ++i)
                #pragma unroll
                for (int j = 0; j < 2; ++j)
                    acc[i][j] = __builtin_amdgcn_mfma_f32_16x16x32_bf16(af[i], bf[j], acc[i][j], 0, 0, 0);
        }
        __syncthreads();
    }

    #pragma unroll
    for (int i = 0; i < 4; ++i) {
        #pragma unroll
        for (int j = 0; j < 2; ++j) {
            #pragma unroll
            for (int reg = 0; reg < 4; ++reg) {
                const int m = m0 + wr + i * 16 + quad * 4 + reg;
                const int n = n0 + wc + j * 16 + r16;
                out[(size_t)m * DMODEL + n] = acc[i][j][reg] + bo[n];
            }
        }
    }
}

// Generic MFMA GEMM — low-ws fallback only (R13/R14-validated).
__global__ __launch_bounds__(256)
void gemm_mfma(const void* __restrict__ A, const void* __restrict__ W,
               const float* __restrict__ bias, void* __restrict__ out,
               int amode, int bmode, int outmode, float oscale)
{
    __shared__ ushort Ash[128][40];
    __shared__ ushort Bsh[128][40];

    const int t    = threadIdx.x;
    const int m0   = blockIdx.y * 128, n0 = blockIdx.x * 128;
    const int srow = t >> 1;
    const int shal = (t & 1) * 16;

    const int wave = t >> 6;
    const int lane = t & 63;
    const int wr   = (wave >> 1) * 64;
    const int wc   = (wave & 1) * 64;
    const int quad = lane >> 4;
    const int r16  = lane & 15;

    f32x4 acc[4][4];
    #pragma unroll
    for (int i = 0; i < 4; ++i)
        #pragma unroll
        for (int j = 0; j < 4; ++j)
            acc[i][j] = (f32x4){0.f, 0.f, 0.f, 0.f};

    for (int k0 = 0; k0 < DMODEL; k0 += 32) {
        uint4 a01, a23, b01, b23;
        if (amode == 0) {
            const float* ap = (const float*)A + (size_t)(m0 + srow) * DMODEL + k0 + shal;
            const float4 f0 = *(const float4*)(ap);
            const float4 f1 = *(const float4*)(ap + 4);
            const float4 f2 = *(const float4*)(ap + 8);
            const float4 f3 = *(const float4*)(ap + 12);
            a01 = (uint4){pk2(f0.x,f0.y), pk2(f0.z,f0.w), pk2(f1.x,f1.y), pk2(f1.z,f1.w)};
            a23 = (uint4){pk2(f2.x,f2.y), pk2(f2.z,f2.w), pk2(f3.x,f3.y), pk2(f3.z,f3.w)};
        } else if (amode == 1) {
            const int m = m0 + srow;
            const ushort* ap = (const ushort*)A
                + ((size_t)(m >> 11) * NH + (k0 >> 6)) * (SEQ * DKH)
                + (size_t)(m & (SEQ - 1)) * DKH + (k0 & 63) + shal;
            a01 = *(const uint4*)(ap);
            a23 = *(const uint4*)(ap + 8);
        } else {
            const ushort* ap = (const ushort*)A + (size_t)(m0 + srow) * DMODEL + k0 + shal;
            a01 = *(const uint4*)(ap);
            a23 = *(const uint4*)(ap + 8);
        }
        if (bmode == 0) {
            const float* wp = (const float*)W + (size_t)(n0 + srow) * DMODEL + k0 + shal;
            const float4 w0 = *(const float4*)(wp);
            const float4 w1 = *(const float4*)(wp + 4);
            const float4 w2 = *(const float4*)(wp + 8);
            const float4 w3 = *(const float4*)(wp + 12);
            b01 = (uint4){pk2(w0.x,w0.y), pk2(w0.z,w0.w), pk2(w1.x,w1.y), pk2(w1.z,w1.w)};
            b23 = (uint4){pk2(w2.x,w2.y), pk2(w2.z,w2.w), pk2(w3.x,w3.y), pk2(w3.z,w3.w)};
        } else {
            const ushort* wp = (const ushort*)W + (size_t)(n0 + srow) * DMODEL + k0 + shal;
            b01 = *(const uint4*)(wp);
            b23 = *(const uint4*)(wp + 8);
        }

        *(uint4*)&Ash[srow][shal]     = a01;
        *(uint4*)&Ash[srow][shal + 8] = a23;
        *(uint4*)&Bsh[srow][shal]     = b01;
        *(uint4*)&Bsh[srow][shal + 8] = b23;
        __syncthreads();

        short8 af[4], bf[4];
        #pragma unroll
        for (int i = 0; i < 4; ++i) af[i] = *(const short8*)&Ash[wr + i * 16 + r16][quad * 8];
        #pragma unroll
        for (int j = 0; j < 4; ++j) bf[j] = *(const short8*)&Bsh[wc + j * 16 + r16][quad * 8];

        #pragma unroll
        for (int i = 0; i < 4; ++i)
            #pragma unroll
            for (int j = 0; j < 4; ++j)
                acc[i][j] = __builtin_amdgcn_mfma_f32_16x16x32_bf16(af[i], bf[j], acc[i][j], 0, 0, 0);
        __syncthreads();
    }

    #pragma unroll
    for (int i = 0; i < 4; ++i) {
        #pragma unroll
        for (int j = 0; j < 4; ++j) {
            #pragma unroll
            for (int reg = 0; reg < 4; ++reg) {
                const int m = m0 + wr + i * 16 + quad * 4 + reg;
                const int n = n0 + wc + j * 16 + r16;
                const float v = (acc[i][j][reg] + bias[n]) * oscale;
                if (outmode == 0) {
                    ((float*)out)[(size_t)m * DMODEL + n] = v;
                } else if (outmode == 1) {
                    ((ushort*)out)[((size_t)(m >> 11) * NH + (n >> 6)) * (SEQ * DKH)
                                   + (size_t)(m & (SEQ - 1)) * DKH + (n & 63)] = f2bf(v);
                } else {
                    ((ushort*)out)[(((size_t)(m >> 11) * NH + (n >> 6)) * DKH + (n & 63)) * SEQ
                                   + (m & (SEQ - 1))] = f2bf(v);
                }
            }
        }
    }
}

// MFMA flash attention: BN=128, XCD-swizzled, max-free softmax, PAIRED
// q-tiles (uniform 33 K-tiles/block; R17-validated at 56.4 us — R18's
// unpaired variant regressed: heavy blocks dispatch last -> makespan tail).
__global__ __launch_bounds__(256)
void attn_flash(ushort* __restrict__ Qh,
                const ushort* __restrict__ Kh,
                const ushort* __restrict__ VT)
{
    __shared__ ushort Kl[128][72];
    __shared__ ushort Vl[64][136];
    __shared__ ushort Pl[4][16][136];

    const int t256 = threadIdx.x;
    const int wave = t256 >> 6;
    const int lane = t256 & 63;
    const int quad = lane >> 4;
    const int r16  = lane & 15;

    const int slot = blockIdx.x & 7;
    const int rest = blockIdx.x >> 3;
    const int bh   = slot * 4 + (rest & 3);
    const int p    = rest >> 2;

    ushort*       Qbase = Qh + (size_t)bh * SEQ * DKH;
    const ushort* Kbase = Kh + (size_t)bh * SEQ * DKH;
    const ushort* Vbase = VT + (size_t)bh * DKH * SEQ;

    #pragma unroll
    for (int pass = 0; pass < 2; ++pass) {
        const int qt = pass ? (31 - p) : p;
        const int q0 = qt * 64;

        short8 qf[2];
        {
            const ushort* qrow = Qbase + (size_t)(q0 + wave * 16 + r16) * DKH;
            qf[0] = *(const short8*)(qrow + quad * 8);
            qf[1] = *(const short8*)(qrow + 32 + quad * 8);
        }

        f32x4 oacc[4];
        #pragma unroll
        for (int i = 0; i < 4; ++i) oacc[i] = (f32x4){0.f, 0.f, 0.f, 0.f};
        float lpart[4] = {0.f, 0.f, 0.f, 0.f};

        const int T   = (qt >> 1) + 1;
        const int off = (qt & 1) * 64;

        for (int t = 0; t < T; ++t) {
            {
                const int krow = t256 >> 1, kc = (t256 & 1) * 32;
                const ushort* kg = Kbase + (size_t)(t * 128 + krow) * DKH + kc;
                *(uint4*)&Kl[krow][kc]      = *(const uint4*)(kg);
                *(uint4*)&Kl[krow][kc + 8]  = *(const uint4*)(kg + 8);
                *(uint4*)&Kl[krow][kc + 16] = *(const uint4*)(kg + 16);
                *(uint4*)&Kl[krow][kc + 24] = *(const uint4*)(kg + 24);
                const int vrow = t256 >> 2, vc = (t256 & 3) * 32;
                const ushort* vg = Vbase + (size_t)vrow * SEQ + t * 128 + vc;
                *(uint4*)&Vl[vrow][vc]      = *(const uint4*)(vg);
                *(uint4*)&Vl[vrow][vc + 8]  = *(const uint4*)(vg + 8);
                *(uint4*)&Vl[vrow][vc + 16] = *(const uint4*)(vg + 16);
                *(uint4*)&Vl[vrow][vc + 24] = *(const uint4*)(vg + 24);
            }
            __syncthreads();

            f32x4 sacc[8];
            #pragma unroll
            for (int nt = 0; nt < 8; ++nt) {
                sacc[nt] = (f32x4){0.f, 0.f, 0.f, 0.f};
                short8 b0 = *(const short8*)&Kl[nt * 16 + r16][quad * 8];
                short8 b1 = *(const short8*)&Kl[nt * 16 + r16][32 + quad * 8];
                sacc[nt] = __builtin_amdgcn_mfma_f32_16x16x32_bf16(qf[0], b0, sacc[nt], 0, 0, 0);
                sacc[nt] = __builtin_amdgcn_mfma_f32_16x16x32_bf16(qf[1], b1, sacc[nt], 0, 0, 0);
            }

            const bool diag = (t == T - 1);
            #pragma unroll
            for (int reg = 0; reg < 4; ++reg) {
                const int row_local = wave * 16 + quad * 4 + reg + off;
                #pragma unroll
                for (int nt = 0; nt < 8; ++nt) {
                    float pv = __expf(sacc[nt][reg]);
                    if (diag && (nt * 16 + r16) > row_local) pv = 0.f;
                    lpart[reg] += pv;
                    Pl[wave][quad * 4 + reg][nt * 16 + r16] = f2bf(pv);
                }
            }

            #pragma unroll
            for (int c = 0; c < 4; ++c) {
                short8 af = *(const short8*)&Pl[wave][r16][c * 32 + quad * 8];
                #pragma unroll
                for (int ct = 0; ct < 4; ++ct) {
                    short8 bf = *(const short8*)&Vl[ct * 16 + r16][c * 32 + quad * 8];
                    oacc[ct] = __builtin_amdgcn_mfma_f32_16x16x32_bf16(af, bf, oacc[ct], 0, 0, 0);
                }
            }
            __syncthreads();
        }

        #pragma unroll
        for (int reg = 0; reg < 4; ++reg)
            for (int d = 1; d < 16; d <<= 1)
                lpart[reg] += __shfl_xor(lpart[reg], d, 64);

        #pragma unroll
        for (int reg = 0; reg < 4; ++reg) {
            const float inv = 1.f / lpart[reg];
            const int q = q0 + wave * 16 + quad * 4 + reg;
            ushort* orow = Qbase + (size_t)q * DKH;
            #pragma unroll
            for (int ct = 0; ct < 4; ++ct)
                orow[ct * 16 + r16] = f2bf(oacc[ct][reg] * inv);
        }
        __syncthreads();
    }
}

extern "C" void kernel_launch(void* const* d_in, const int* in_sizes, int n_in,
                              void* d_out, int out_size, void* d_ws, size_t ws_size,
                              hipStream_t stream)
{
    // Settled: documented dict order; inputs fp32; output fp32; mask unused;
    // ws >= 24 MiB.
    const float* x  = (const float*)d_in[0];
    const float* Wf[4] = {(const float*)d_in[2], (const float*)d_in[4],
                          (const float*)d_in[6], (const float*)d_in[8]};
    const float* Bf[4] = {(const float*)d_in[3], (const float*)d_in[5],
                          (const float*)d_in[7], (const float*)d_in[9]};

    const size_t HSZ = (size_t)MROWS * DMODEL;
    ushort* Qh = (ushort*)d_ws;
    ushort* Kh = (ushort*)d_out;
    ushort* VT = (ushort*)d_out + HSZ;

    const dim3 blk(256);

    if (ws_size >= 24u * 1024 * 1024) {
        ushort* Wcat = Qh + HSZ;
        ushort* Wo   = Wcat + 3 * (size_t)WELEM;
        ushort* xbf  = Wo + WELEM;

        cvt_all<<<dim3(4096), blk, 0, stream>>>(x, Wf[0], Wf[1], Wf[2], Wf[3],
                                                xbf, Wcat, Wo);

        gemm_qkv<<<dim3(3 * DMODEL / 128, MROWS / 128), blk, 0, stream>>>(
            xbf, Wcat, Bf[0], Bf[1], Bf[2], Qh, Kh, VT);

        attn_flash<<<dim3(BSZ * NH * 16), blk, 0, stream>>>(Qh, Kh, VT);

        gemm_out<<<dim3(DMODEL / 64, MROWS / 128), blk, 0, stream>>>(
            Qh, Wo, Bf[3], (float*)d_out);
    } else {
        const dim3 gg(DMODEL / 128, MROWS / 128);
        gemm_mfma<<<gg, blk, 0, stream>>>(x, Wf[0], Bf[0], Qh, 0, 0, 1, 0.125f);
        gemm_mfma<<<gg, blk, 0, stream>>>(x, Wf[1], Bf[1], Kh, 0, 0, 1, 1.0f);
        gemm_mfma<<<gg, blk, 0, stream>>>(x, Wf[2], Bf[2], VT, 0, 0, 2, 1.0f);
        attn_flash<<<dim3(BSZ * NH * 16), blk, 0, stream>>>(Qh, Kh, VT);
        gemm_mfma<<<gg, blk, 0, stream>>>(Qh, Wf[3], Bf[3], d_out, 1, 0, 0, 1.0f);
    }
}

// Round 20
// 219.433 us; speedup vs baseline: 1.0383x; 1.0383x over previous
//
#include <hip/hip_runtime.h>
#include <hip/hip_bf16.h>

#define DMODEL 1024
#define NH     16
#define DKH    64
#define BSZ    2
#define SEQ    2048
#define MROWS  (BSZ*SEQ)      // 4096
#define WELEM  (DMODEL*DMODEL)

typedef __attribute__((ext_vector_type(8))) short short8;
typedef __attribute__((ext_vector_type(4))) float f32x4;

__device__ __forceinline__ ushort f2bf(float f) {
    return __bfloat16_as_ushort(__float2bfloat16(f));
}
__device__ __forceinline__ unsigned pk2(float lo, float hi) {
    return (unsigned)f2bf(lo) | ((unsigned)f2bf(hi) << 16);
}
// Async global->LDS, 16 B/lane. LDS dest = wave-uniform base + lane*16.
__device__ __forceinline__ void load_lds16(const ushort* g, ushort* l) {
    __builtin_amdgcn_global_load_lds(
        (const __attribute__((address_space(1))) unsigned int*)g,
        (__attribute__((address_space(3))) unsigned int*)l, 16, 0, 0);
}
// Key permutation within a 128-key tile (applied to BOTH P cols and V rows;
// softmax@V is invariant). Makes attn's P-store a contiguous b128.
__device__ __forceinline__ int kperm(int s) {
    return (s & ~127) | (((s & 15) << 3) | ((s >> 4) & 7));
}

// Merged fp32->bf16 conversion (R17-validated).
__global__ __launch_bounds__(256)
void cvt_all(const float* __restrict__ x,
             const float* __restrict__ W0, const float* __restrict__ W1,
             const float* __restrict__ W2, const float* __restrict__ W3,
             ushort* __restrict__ xbf, ushort* __restrict__ Wcat,
             ushort* __restrict__ Wo)
{
    const int blk = blockIdx.x;
    const float* src;
    ushort* dst;
    int base;
    if (blk < 2048)      { src = x;  dst = xbf;             base = blk * 2048; }
    else if (blk < 2560) { src = W0; dst = Wcat;            base = (blk - 2048) * 2048; }
    else if (blk < 3072) { src = W1; dst = Wcat + WELEM;    base = (blk - 2560) * 2048; }
    else if (blk < 3584) { src = W2; dst = Wcat + 2*WELEM;  base = (blk - 3072) * 2048; }
    else                 { src = W3; dst = Wo;              base = (blk - 3584) * 2048; }
    const size_t off = (size_t)base + threadIdx.x * 8;
    const float4 f0 = *(const float4*)(src + off);
    const float4 f1 = *(const float4*)(src + off + 4);
    uint4 o;
    o.x = pk2(f0.x, f0.y); o.y = pk2(f0.z, f0.w);
    o.z = pk2(f1.x, f1.y); o.w = pk2(f1.z, f1.w);
    *(uint4*)(dst + off) = o;
}

// FUSED QKV GEMM — R18 BK=32 async form (validated; R19's BK=64 regressed via
// occupancy). Region 0 (Q) PRE-SCALED by 1/8. Region 2 writes PERMUTED V^T.
__global__ __launch_bounds__(256)
void gemm_qkv(const ushort* __restrict__ xbf, const ushort* __restrict__ Wcat,
              const float* __restrict__ bq, const float* __restrict__ bk,
              const float* __restrict__ bv,
              ushort* __restrict__ Qh, ushort* __restrict__ Kh,
              ushort* __restrict__ VT)
{
    __shared__ ushort Ash[128][32];
    __shared__ ushort Bsh[128][32];

    const int t    = threadIdx.x;
    const int m0   = blockIdx.y * 128, n0 = blockIdx.x * 128;
    const int wave = t >> 6;
    const int lane = t & 63;
    const int wr   = (wave >> 1) * 64;
    const int wc   = (wave & 1) * 64;
    const int quad = lane >> 4;
    const int r16  = lane & 15;

    const int row0 = wave * 16 + (lane >> 2);
    const int row1 = 64 + wave * 16 + (lane >> 2);
    const int ch   = (lane & 3) * 8;

    f32x4 acc[4][4];
    #pragma unroll
    for (int i = 0; i < 4; ++i)
        #pragma unroll
        for (int j = 0; j < 4; ++j)
            acc[i][j] = (f32x4){0.f, 0.f, 0.f, 0.f};

    for (int k0 = 0; k0 < DMODEL; k0 += 32) {
        load_lds16(xbf  + (size_t)(m0 + row0) * DMODEL + k0 + ch, &Ash[wave * 16][0]);
        load_lds16(xbf  + (size_t)(m0 + row1) * DMODEL + k0 + ch, &Ash[64 + wave * 16][0]);
        load_lds16(Wcat + (size_t)(n0 + row0) * DMODEL + k0 + ch, &Bsh[wave * 16][0]);
        load_lds16(Wcat + (size_t)(n0 + row1) * DMODEL + k0 + ch, &Bsh[64 + wave * 16][0]);
        __syncthreads();

        short8 af[4], bf[4];
        #pragma unroll
        for (int i = 0; i < 4; ++i) af[i] = *(const short8*)&Ash[wr + i * 16 + r16][quad * 8];
        #pragma unroll
        for (int j = 0; j < 4; ++j) bf[j] = *(const short8*)&Bsh[wc + j * 16 + r16][quad * 8];

        #pragma unroll
        for (int i = 0; i < 4; ++i)
            #pragma unroll
            for (int j = 0; j < 4; ++j)
                acc[i][j] = __builtin_amdgcn_mfma_f32_16x16x32_bf16(af[i], bf[j], acc[i][j], 0, 0, 0);
        __syncthreads();
    }

    const int region = n0 >> 10;
    const float* bp  = (region == 0) ? bq : (region == 1) ? bk : bv;
    ushort* outQK    = (region == 0) ? Qh : Kh;
    const float osc  = (region == 0) ? 0.125f : 1.0f;
    const int nbase  = n0 & 1023;

    #pragma unroll
    for (int i = 0; i < 4; ++i) {
        #pragma unroll
        for (int j = 0; j < 4; ++j) {
            #pragma unroll
            for (int reg = 0; reg < 4; ++reg) {
                const int m  = m0 + wr + i * 16 + quad * 4 + reg;
                const int n  = nbase + wc + j * 16 + r16;
                const float v = (acc[i][j][reg] + bp[n]) * osc;
                const int b = m >> 11, s = m & (SEQ - 1);
                const int h = n >> 6,  dk = n & 63;
                if (region < 2) {
                    outQK[((size_t)(b * NH + h) * SEQ + s) * DKH + dk] = f2bf(v);
                } else {
                    VT[(((size_t)(b * NH + h)) * DKH + dk) * SEQ + kperm(s)] = f2bf(v);
                }
            }
        }
    }
}

// Output projection — R18 BK=32 async form. O bf16 head-major; out fp32.
__global__ __launch_bounds__(256)
void gemm_out(const ushort* __restrict__ O, const ushort* __restrict__ Wo,
              const float* __restrict__ bo, float* __restrict__ out)
{
    __shared__ ushort Ash[128][32];
    __shared__ ushort Bsh[64][32];

    const int t    = threadIdx.x;
    const int m0   = blockIdx.y * 128, n0 = blockIdx.x * 64;
    const int wave = t >> 6;
    const int lane = t & 63;
    const int wr   = (wave >> 1) * 64;
    const int wc   = (wave & 1) * 32;
    const int quad = lane >> 4;
    const int r16  = lane & 15;

    const int row0 = wave * 16 + (lane >> 2);
    const int row1 = 64 + wave * 16 + (lane >> 2);
    const int ch   = (lane & 3) * 8;

    f32x4 acc[4][2];
    #pragma unroll
    for (int i = 0; i < 4; ++i)
        #pragma unroll
        for (int j = 0; j < 2; ++j)
            acc[i][j] = (f32x4){0.f, 0.f, 0.f, 0.f};

    for (int k0 = 0; k0 < DMODEL; k0 += 32) {
        const int ma0 = m0 + row0, ma1 = m0 + row1;
        load_lds16(O + ((size_t)(ma0 >> 11) * NH + (k0 >> 6)) * (SEQ * DKH)
                     + (size_t)(ma0 & (SEQ - 1)) * DKH + (k0 & 63) + ch,
                   &Ash[wave * 16][0]);
        load_lds16(O + ((size_t)(ma1 >> 11) * NH + (k0 >> 6)) * (SEQ * DKH)
                     + (size_t)(ma1 & (SEQ - 1)) * DKH + (k0 & 63) + ch,
                   &Ash[64 + wave * 16][0]);
        load_lds16(Wo + (size_t)(n0 + row0) * DMODEL + k0 + ch, &Bsh[wave * 16][0]);
        __syncthreads();

        short8 af[4], bf[2];
        #pragma unroll
        for (int i = 0; i < 4; ++i) af[i] = *(const short8*)&Ash[wr + i * 16 + r16][quad * 8];
        #pragma unroll
        for (int j = 0; j < 2; ++j) bf[j] = *(const short8*)&Bsh[wc + j * 16 + r16][quad * 8];

        #pragma unroll
        for (int i = 0; i < 4; ++i)
            #pragma unroll
            for (int j = 0; j < 2; ++j)
                acc[i][j] = __builtin_amdgcn_mfma_f32_16x16x32_bf16(af[i], bf[j], acc[i][j], 0, 0, 0);
        __syncthreads();
    }

    #pragma unroll
    for (int i = 0; i < 4; ++i) {
        #pragma unroll
        for (int j = 0; j < 2; ++j) {
            #pragma unroll
            for (int reg = 0; reg < 4; ++reg) {
                const int m = m0 + wr + i * 16 + quad * 4 + reg;
                const int n = n0 + wc + j * 16 + r16;
                out[(size_t)m * DMODEL + n] = acc[i][j][reg] + bo[n];
            }
        }
    }
}

// Generic MFMA GEMM — low-ws fallback only. outmode 2 uses the SAME key
// permutation as gemm_qkv (attn depends on it).
__global__ __launch_bounds__(256)
void gemm_mfma(const void* __restrict__ A, const void* __restrict__ W,
               const float* __restrict__ bias, void* __restrict__ out,
               int amode, int bmode, int outmode, float oscale)
{
    __shared__ ushort Ash[128][40];
    __shared__ ushort Bsh[128][40];

    const int t    = threadIdx.x;
    const int m0   = blockIdx.y * 128, n0 = blockIdx.x * 128;
    const int srow = t >> 1;
    const int shal = (t & 1) * 16;

    const int wave = t >> 6;
    const int lane = t & 63;
    const int wr   = (wave >> 1) * 64;
    const int wc   = (wave & 1) * 64;
    const int quad = lane >> 4;
    const int r16  = lane & 15;

    f32x4 acc[4][4];
    #pragma unroll
    for (int i = 0; i < 4; ++i)
        #pragma unroll
        for (int j = 0; j < 4; ++j)
            acc[i][j] = (f32x4){0.f, 0.f, 0.f, 0.f};

    for (int k0 = 0; k0 < DMODEL; k0 += 32) {
        uint4 a01, a23, b01, b23;
        if (amode == 0) {
            const float* ap = (const float*)A + (size_t)(m0 + srow) * DMODEL + k0 + shal;
            const float4 f0 = *(const float4*)(ap);
            const float4 f1 = *(const float4*)(ap + 4);
            const float4 f2 = *(const float4*)(ap + 8);
            const float4 f3 = *(const float4*)(ap + 12);
            a01 = (uint4){pk2(f0.x,f0.y), pk2(f0.z,f0.w), pk2(f1.x,f1.y), pk2(f1.z,f1.w)};
            a23 = (uint4){pk2(f2.x,f2.y), pk2(f2.z,f2.w), pk2(f3.x,f3.y), pk2(f3.z,f3.w)};
        } else if (amode == 1) {
            const int m = m0 + srow;
            const ushort* ap = (const ushort*)A
                + ((size_t)(m >> 11) * NH + (k0 >> 6)) * (SEQ * DKH)
                + (size_t)(m & (SEQ - 1)) * DKH + (k0 & 63) + shal;
            a01 = *(const uint4*)(ap);
            a23 = *(const uint4*)(ap + 8);
        } else {
            const ushort* ap = (const ushort*)A + (size_t)(m0 + srow) * DMODEL + k0 + shal;
            a01 = *(const uint4*)(ap);
            a23 = *(const uint4*)(ap + 8);
        }
        if (bmode == 0) {
            const float* wp = (const float*)W + (size_t)(n0 + srow) * DMODEL + k0 + shal;
            const float4 w0 = *(const float4*)(wp);
            const float4 w1 = *(const float4*)(wp + 4);
            const float4 w2 = *(const float4*)(wp + 8);
            const float4 w3 = *(const float4*)(wp + 12);
            b01 = (uint4){pk2(w0.x,w0.y), pk2(w0.z,w0.w), pk2(w1.x,w1.y), pk2(w1.z,w1.w)};
            b23 = (uint4){pk2(w2.x,w2.y), pk2(w2.z,w2.w), pk2(w3.x,w3.y), pk2(w3.z,w3.w)};
        } else {
            const ushort* wp = (const ushort*)W + (size_t)(n0 + srow) * DMODEL + k0 + shal;
            b01 = *(const uint4*)(wp);
            b23 = *(const uint4*)(wp + 8);
        }

        *(uint4*)&Ash[srow][shal]     = a01;
        *(uint4*)&Ash[srow][shal + 8] = a23;
        *(uint4*)&Bsh[srow][shal]     = b01;
        *(uint4*)&Bsh[srow][shal + 8] = b23;
        __syncthreads();

        short8 af[4], bf[4];
        #pragma unroll
        for (int i = 0; i < 4; ++i) af[i] = *(const short8*)&Ash[wr + i * 16 + r16][quad * 8];
        #pragma unroll
        for (int j = 0; j < 4; ++j) bf[j] = *(const short8*)&Bsh[wc + j * 16 + r16][quad * 8];

        #pragma unroll
        for (int i = 0; i < 4; ++i)
            #pragma unroll
            for (int j = 0; j < 4; ++j)
                acc[i][j] = __builtin_amdgcn_mfma_f32_16x16x32_bf16(af[i], bf[j], acc[i][j], 0, 0, 0);
        __syncthreads();
    }

    #pragma unroll
    for (int i = 0; i < 4; ++i) {
        #pragma unroll
        for (int j = 0; j < 4; ++j) {
            #pragma unroll
            for (int reg = 0; reg < 4; ++reg) {
                const int m = m0 + wr + i * 16 + quad * 4 + reg;
                const int n = n0 + wc + j * 16 + r16;
                const float v = (acc[i][j][reg] + bias[n]) * oscale;
                if (outmode == 0) {
                    ((float*)out)[(size_t)m * DMODEL + n] = v;
                } else if (outmode == 1) {
                    ((ushort*)out)[((size_t)(m >> 11) * NH + (n >> 6)) * (SEQ * DKH)
                                   + (size_t)(m & (SEQ - 1)) * DKH + (n & 63)] = f2bf(v);
                } else {
                    ((ushort*)out)[(((size_t)(m >> 11) * NH + (n >> 6)) * DKH + (n & 63)) * SEQ
                                   + kperm(m & (SEQ - 1))] = f2bf(v);
                }
            }
        }
    }
}

// MFMA flash attention: BN=128, XCD-swizzled, max-free softmax, PAIRED
// q-tiles (R17-validated). NEW: P stored in permuted-key layout so each lane
// writes one contiguous b128 per reg (4 ds_write_b128 vs 32 ds_write_u16 per
// tile). V^T arrives pre-permuted from gemm_qkv; fragment reads unchanged.
__global__ __launch_bounds__(256)
void attn_flash(ushort* __restrict__ Qh,
                const ushort* __restrict__ Kh,
                const ushort* __restrict__ VT)
{
    __shared__ ushort Kl[128][72];
    __shared__ ushort Vl[64][136];
    __shared__ ushort Pl[4][16][136];

    const int t256 = threadIdx.x;
    const int wave = t256 >> 6;
    const int lane = t256 & 63;
    const int quad = lane >> 4;
    const int r16  = lane & 15;

    const int slot = blockIdx.x & 7;
    const int rest = blockIdx.x >> 3;
    const int bh   = slot * 4 + (rest & 3);
    const int p    = rest >> 2;

    ushort*       Qbase = Qh + (size_t)bh * SEQ * DKH;
    const ushort* Kbase = Kh + (size_t)bh * SEQ * DKH;
    const ushort* Vbase = VT + (size_t)bh * DKH * SEQ;

    #pragma unroll
    for (int pass = 0; pass < 2; ++pass) {
        const int qt = pass ? (31 - p) : p;
        const int q0 = qt * 64;

        short8 qf[2];
        {
            const ushort* qrow = Qbase + (size_t)(q0 + wave * 16 + r16) * DKH;
            qf[0] = *(const short8*)(qrow + quad * 8);
            qf[1] = *(const short8*)(qrow + 32 + quad * 8);
        }

        f32x4 oacc[4];
        #pragma unroll
        for (int i = 0; i < 4; ++i) oacc[i] = (f32x4){0.f, 0.f, 0.f, 0.f};
        float lpart[4] = {0.f, 0.f, 0.f, 0.f};

        const int T   = (qt >> 1) + 1;
        const int off = (qt & 1) * 64;

        for (int t = 0; t < T; ++t) {
            {
                const int krow = t256 >> 1, kc = (t256 & 1) * 32;
                const ushort* kg = Kbase + (size_t)(t * 128 + krow) * DKH + kc;
                *(uint4*)&Kl[krow][kc]      = *(const uint4*)(kg);
                *(uint4*)&Kl[krow][kc + 8]  = *(const uint4*)(kg + 8);
                *(uint4*)&Kl[krow][kc + 16] = *(const uint4*)(kg + 16);
                *(uint4*)&Kl[krow][kc + 24] = *(const uint4*)(kg + 24);
                const int vrow = t256 >> 2, vc = (t256 & 3) * 32;
                const ushort* vg = Vbase + (size_t)vrow * SEQ + t * 128 + vc;
                *(uint4*)&Vl[vrow][vc]      = *(const uint4*)(vg);
                *(uint4*)&Vl[vrow][vc + 8]  = *(const uint4*)(vg + 8);
                *(uint4*)&Vl[vrow][vc + 16] = *(const uint4*)(vg + 16);
                *(uint4*)&Vl[vrow][vc + 24] = *(const uint4*)(vg + 24);
            }
            __syncthreads();

            f32x4 sacc[8];
            #pragma unroll
            for (int nt = 0; nt < 8; ++nt) {
                sacc[nt] = (f32x4){0.f, 0.f, 0.f, 0.f};
                short8 b0 = *(const short8*)&Kl[nt * 16 + r16][quad * 8];
                short8 b1 = *(const short8*)&Kl[nt * 16 + r16][32 + quad * 8];
                sacc[nt] = __builtin_amdgcn_mfma_f32_16x16x32_bf16(qf[0], b0, sacc[nt], 0, 0, 0);
                sacc[nt] = __builtin_amdgcn_mfma_f32_16x16x32_bf16(qf[1], b1, sacc[nt], 0, 0, 0);
            }

            // exp + diag mask + partial row-sum; P stored permuted: storage
            // col for key (nt*16+r16) is (r16*8+nt) -> contiguous b128/reg.
            const bool diag = (t == T - 1);
            #pragma unroll
            for (int reg = 0; reg < 4; ++reg) {
                const int row_local = wave * 16 + quad * 4 + reg + off;
                short8 p8;
                #pragma unroll
                for (int nt = 0; nt < 8; ++nt) {
                    float pv = __expf(sacc[nt][reg]);
                    if (diag && (nt * 16 + r16) > row_local) pv = 0.f;
                    lpart[reg] += pv;
                    p8[nt] = (short)f2bf(pv);
                }
                *(short8*)&Pl[wave][quad * 4 + reg][r16 * 8] = p8;
            }

            #pragma unroll
            for (int c = 0; c < 4; ++c) {
                short8 af = *(const short8*)&Pl[wave][r16][c * 32 + quad * 8];
                #pragma unroll
                for (int ct = 0; ct < 4; ++ct) {
                    short8 bf = *(const short8*)&Vl[ct * 16 + r16][c * 32 + quad * 8];
                    oacc[ct] = __builtin_amdgcn_mfma_f32_16x16x32_bf16(af, bf, oacc[ct], 0, 0, 0);
                }
            }
            __syncthreads();
        }

        #pragma unroll
        for (int reg = 0; reg < 4; ++reg)
            for (int d = 1; d < 16; d <<= 1)
                lpart[reg] += __shfl_xor(lpart[reg], d, 64);

        #pragma unroll
        for (int reg = 0; reg < 4; ++reg) {
            const float inv = 1.f / lpart[reg];
            const int q = q0 + wave * 16 + quad * 4 + reg;
            ushort* orow = Qbase + (size_t)q * DKH;
            #pragma unroll
            for (int ct = 0; ct < 4; ++ct)
                orow[ct * 16 + r16] = f2bf(oacc[ct][reg] * inv);
        }
        __syncthreads();
    }
}

extern "C" void kernel_launch(void* const* d_in, const int* in_sizes, int n_in,
                              void* d_out, int out_size, void* d_ws, size_t ws_size,
                              hipStream_t stream)
{
    // Settled: documented dict order; inputs fp32; output fp32; mask unused;
    // ws >= 24 MiB.
    const float* x  = (const float*)d_in[0];
    const float* Wf[4] = {(const float*)d_in[2], (const float*)d_in[4],
                          (const float*)d_in[6], (const float*)d_in[8]};
    const float* Bf[4] = {(const float*)d_in[3], (const float*)d_in[5],
                          (const float*)d_in[7], (const float*)d_in[9]};

    const size_t HSZ = (size_t)MROWS * DMODEL;
    ushort* Qh = (ushort*)d_ws;
    ushort* Kh = (ushort*)d_out;
    ushort* VT = (ushort*)d_out + HSZ;

    const dim3 blk(256);

    if (ws_size >= 24u * 1024 * 1024) {
        ushort* Wcat = Qh + HSZ;
        ushort* Wo   = Wcat + 3 * (size_t)WELEM;
        ushort* xbf  = Wo + WELEM;

        cvt_all<<<dim3(4096), blk, 0, stream>>>(x, Wf[0], Wf[1], Wf[2], Wf[3],
                                                xbf, Wcat, Wo);

        gemm_qkv<<<dim3(3 * DMODEL / 128, MROWS / 128), blk, 0, stream>>>(
            xbf, Wcat, Bf[0], Bf[1], Bf[2], Qh, Kh, VT);

        attn_flash<<<dim3(BSZ * NH * 16), blk, 0, stream>>>(Qh, Kh, VT);

        gemm_out<<<dim3(DMODEL / 64, MROWS / 128), blk, 0, stream>>>(
            Qh, Wo, Bf[3], (float*)d_out);
    } else {
        const dim3 gg(DMODEL / 128, MROWS / 128);
        gemm_mfma<<<gg, blk, 0, stream>>>(x, Wf[0], Bf[0], Qh, 0, 0, 1, 0.125f);
        gemm_mfma<<<gg, blk, 0, stream>>>(x, Wf[1], Bf[1], Kh, 0, 0, 1, 1.0f);
        gemm_mfma<<<gg, blk, 0, stream>>>(x, Wf[2], Bf[2], VT, 0, 0, 2, 1.0f);
        attn_flash<<<dim3(BSZ * NH * 16), blk, 0, stream>>>(Qh, Kh, VT);
        gemm_mfma<<<gg, blk, 0, stream>>>(Qh, Wf[3], Bf[3], d_out, 1, 0, 0, 1.0f);
    }
}